// Round 4
// baseline (456.381 us; speedup 1.0000x reference)
//
#include <hip/hip_runtime.h>
#include <math.h>

#define T_STEPS 32
#define NB 64      // batch
#define CC 512     // channels
#define AA 32      // cc_acc size

__device__ __forceinline__ float sig_decay(const float* wp) {
    // decay = 1 - sigmoid(w)
    return 1.0f - 1.0f / (1.0f + expf(-wp[0]));
}

// ---------------------------------------------------------------------------
// Front end: transpose + synapse(tau=2) + jeffress(2->32) + LIF(1.5) +
// synapse(sf0) + w_cc(32->1) + IF + synapse(sf1).  One thread per (n,c),
// loops t; all recurrent state in registers.  Writes y7 (T*N, 512).
// ---------------------------------------------------------------------------
__global__ __launch_bounds__(256) void front_kernel(
    const float* __restrict__ x, const float* __restrict__ w_jeff,
    const float* __restrict__ w_cc, const float* __restrict__ w_sf0,
    const float* __restrict__ w_sf1, float* __restrict__ y7)
{
    __shared__ float wj[2 * AA];
    __shared__ float wcc[AA];
    int tid = threadIdx.x;
    if (tid < 2 * AA) wj[tid] = w_jeff[tid];
    if (tid < AA) wcc[tid] = w_cc[tid];
    __syncthreads();

    int g = blockIdx.x * 256 + tid;     // n*CC + c
    int n = g >> 9;
    int c = g & (CC - 1);

    const float inv_lif = 1.0f / 1.5f;
    float d0 = sig_decay(w_sf0);
    float d1 = sig_decay(w_sf1);

    float s0 = 0.f, s1 = 0.f, v6 = 0.f, u1 = 0.f;
    float v[AA], u[AA];
#pragma unroll
    for (int a = 0; a < AA; a++) { v[a] = 0.f; u[a] = 0.f; }

    for (int t = 0; t < T_STEPS; t++) {
        const float* xp = x + (size_t)((t * NB + n) * 2) * CC + c;
        s0 = s0 * 0.5f + xp[0];     // synapse filter, tau=2 (decay 0.5)
        s1 = s1 * 0.5f + xp[CC];
        float acc = 0.f;
#pragma unroll
        for (int a = 0; a < AA; a++) {
            float z  = wj[2 * a] * s0 + wj[2 * a + 1] * s1;
            float vv = v[a] + (z - v[a]) * inv_lif;   // LIF decay_input
            bool  sp = vv >= 1.0f;
            v[a] = sp ? 0.0f : vv;                    // hard reset
            float uu = u[a] * d0 + (sp ? 1.0f : 0.0f);
            u[a] = uu;
            acc += wcc[a] * uu;
        }
        v6 += acc;                                    // IFNode
        bool sp6 = v6 >= 1.0f;
        v6 = sp6 ? 0.0f : v6;
        u1 = u1 * d1 + (sp6 ? 1.0f : 0.0f);           // sf1 filter
        y7[(size_t)(t * NB + n) * CC + c] = u1;
    }
}

// ---------------------------------------------------------------------------
// IF (+ optional synapse filter) over the (deterministic, in-order) sum of
// `nparts` split-K partial buffers.  Result written in place into part 0.
// One thread per (n,f), loop t.  w_sf == nullptr -> emit raw spikes.
// ---------------------------------------------------------------------------
__global__ __launch_bounds__(256) void if_filter_kernel(
    float* __restrict__ buf, size_t partStride, int nparts,
    const float* __restrict__ w_sf, int F)
{
    int tid = blockIdx.x * 256 + threadIdx.x;   // n*F + f
    const int NF = NB * F;
    bool  filt = (w_sf != nullptr);
    float d = filt ? sig_decay(w_sf) : 0.0f;
    float v = 0.f, u = 0.f;
    for (int t = 0; t < T_STEPS; t++) {
        size_t off = (size_t)t * NF + tid;
        float zt = buf[off];
        for (int p = 1; p < nparts; p++) zt += buf[p * partStride + off];
        v += zt;
        bool sp = v >= 1.0f;
        v = sp ? 0.0f : v;
        float s = sp ? 1.0f : 0.0f;
        if (filt) { u = u * d + s; buf[off] = u; }
        else      { buf[off] = s; }
    }
}

// ---------------------------------------------------------------------------
// C = A * B^T, split-K.  A: (M,K) row-major, B: (N,K) row-major.
// Partial for split s goes to C + s*M*N over K range [s*K_per, (s+1)*K_per).
// 128x128 block, BK=16, 256 threads as 16x16, 8x8 micro-tile (2 FLOP per
// LDS byte; A-frag reads broadcast).  Double-buffered LDS + register
// prefetch — occupancy is grid-limited (1 block/CU), so VGPRs are free.
// ---------------------------------------------------------------------------
__global__ __launch_bounds__(256) void gemm_nt(
    const float* __restrict__ A, const float* __restrict__ B,
    float* __restrict__ C, int M, int N, int K_total, int K_per)
{
    constexpr int BM = 128, BN = 128, BK = 16;
    __shared__ float As[2][BK][BM + 4];   // transposed: As[b][kk][row]
    __shared__ float Bs[2][BK][BN + 4];

    const int tid = threadIdx.x;
    const int tx  = tid & 15;        // col group (8 cols each)
    const int ty  = tid >> 4;        // row group (8 rows each)
    const int bm  = blockIdx.y * BM;
    const int bn  = blockIdx.x * BN;
    const int s   = blockIdx.z;
    const int kbeg = s * K_per;

    // staging loads: BM*BK/256 = 8 floats = 2 float4 per thread (A and B)
    const int lrow = tid >> 2;       // 0..63
    const int lkq  = tid & 3;        // k-quad

    float4 aReg[2], bReg[2];
    auto load_regs = [&](int k0) {
#pragma unroll
        for (int i = 0; i < 2; i++) {
            int row = lrow + i * 64;
            aReg[i] = *(const float4*)(A + (size_t)(bm + row) * K_total + k0 + lkq * 4);
            bReg[i] = *(const float4*)(B + (size_t)(bn + row) * K_total + k0 + lkq * 4);
        }
    };
    auto store_lds = [&](int b) {
#pragma unroll
        for (int i = 0; i < 2; i++) {
            int row = lrow + i * 64;
            As[b][lkq * 4 + 0][row] = aReg[i].x;
            As[b][lkq * 4 + 1][row] = aReg[i].y;
            As[b][lkq * 4 + 2][row] = aReg[i].z;
            As[b][lkq * 4 + 3][row] = aReg[i].w;
            Bs[b][lkq * 4 + 0][row] = bReg[i].x;
            Bs[b][lkq * 4 + 1][row] = bReg[i].y;
            Bs[b][lkq * 4 + 2][row] = bReg[i].z;
            Bs[b][lkq * 4 + 3][row] = bReg[i].w;
        }
    };

    float acc[8][8];
#pragma unroll
    for (int i = 0; i < 8; i++)
#pragma unroll
        for (int j = 0; j < 8; j++) acc[i][j] = 0.f;

    load_regs(kbeg);
    store_lds(0);
    __syncthreads();

    const int nk = K_per / BK;
    for (int kt = 0; kt < nk; kt++) {
        int cur = kt & 1;
        bool has_next = (kt + 1 < nk);
        if (has_next) load_regs(kbeg + (kt + 1) * BK);   // prefetch (hidden)
#pragma unroll
        for (int kk = 0; kk < BK; kk++) {
            float4 a0 = *(const float4*)&As[cur][kk][ty * 8];
            float4 a1 = *(const float4*)&As[cur][kk][ty * 8 + 4];
            float4 b0 = *(const float4*)&Bs[cur][kk][tx * 8];
            float4 b1 = *(const float4*)&Bs[cur][kk][tx * 8 + 4];
            float ar[8] = {a0.x, a0.y, a0.z, a0.w, a1.x, a1.y, a1.z, a1.w};
            float br[8] = {b0.x, b0.y, b0.z, b0.w, b1.x, b1.y, b1.z, b1.w};
#pragma unroll
            for (int i = 0; i < 8; i++)
#pragma unroll
                for (int j = 0; j < 8; j++) acc[i][j] += ar[i] * br[j];
        }
        if (has_next) {
            store_lds(cur ^ 1);      // other buffer: safe, readers passed
            __syncthreads();
        }
    }

    float* Cp = C + (size_t)s * M * N;
#pragma unroll
    for (int i = 0; i < 8; i++) {
        float* cp = Cp + (size_t)(bm + ty * 8 + i) * N + bn + tx * 8;
        float4 o0, o1;
        o0.x = acc[i][0]; o0.y = acc[i][1]; o0.z = acc[i][2]; o0.w = acc[i][3];
        o1.x = acc[i][4]; o1.y = acc[i][5]; o1.z = acc[i][6]; o1.w = acc[i][7];
        *(float4*)cp = o0;
        *(float4*)(cp + 4) = o1;
    }
}

// ---------------------------------------------------------------------------
// Final: out[t,n] = cumsum_t( dot(y15[t,n,:512], W_out) + b ).
// One wave (64 threads) per n.
// ---------------------------------------------------------------------------
__global__ __launch_bounds__(64) void final_kernel(
    const float* __restrict__ y15, const float* __restrict__ W_out,
    const float* __restrict__ b_out, float* __restrict__ out)
{
    int n = blockIdx.x;
    int lane = threadIdx.x;
    float w[8];
#pragma unroll
    for (int j = 0; j < 8; j++) w[j] = W_out[lane + j * 64];
    float b = b_out[0];
    float cum = 0.f;
    for (int t = 0; t < T_STEPS; t++) {
        const float* yp = y15 + (size_t)(t * NB + n) * 512;
        float p = 0.f;
#pragma unroll
        for (int j = 0; j < 8; j++) p += yp[lane + j * 64] * w[j];
#pragma unroll
        for (int off = 32; off > 0; off >>= 1) p += __shfl_down(p, off);
        if (lane == 0) {
            cum += p + b;
            out[t * NB + n] = cum;
        }
    }
}

extern "C" void kernel_launch(void* const* d_in, const int* in_sizes, int n_in,
                              void* d_out, int out_size, void* d_ws, size_t ws_size,
                              hipStream_t stream) {
    (void)in_sizes; (void)n_in; (void)out_size;
    const float* x      = (const float*)d_in[0];
    const float* w_jeff = (const float*)d_in[1];
    const float* w_cc   = (const float*)d_in[2];
    const float* w_sf0  = (const float*)d_in[3];
    const float* W1     = (const float*)d_in[4];
    const float* w_sf1  = (const float*)d_in[5];
    const float* W2     = (const float*)d_in[6];
    const float* w_sf2  = (const float*)d_in[7];
    const float* W3     = (const float*)d_in[8];
    const float* w_sf3  = (const float*)d_in[9];
    const float* W_out  = (const float*)d_in[10];
    const float* b_out  = (const float*)d_in[11];
    float* out = (float*)d_out;

    const int M = T_STEPS * NB;                 // 2048
    // ws layout (floats):
    //   y7  : M*512              (front-end output / GEMM1 A)
    //   z1  : M*2048             (GEMM1 out; later reused for GEMM3 partials)
    //   z2p : ksplit2 * M*1024   (GEMM2 split-K partials; result in part 0)
    // GEMM3 partials (4 * M*512 = M*2048 floats) overlay z1 (dead by then).
    float* y7  = (float*)d_ws;
    float* z1  = y7 + (size_t)M * 512;
    float* z2p = z1 + (size_t)M * 2048;
    float* z3p = z1;                            // overlay

    size_t need2 = ((size_t)M * 512 + (size_t)M * 2048 + 2 * (size_t)M * 1024) * 4;
    const int ksplit2 = (ws_size >= need2) ? 2 : 1;

    // 1. front end -> y7
    front_kernel<<<NB * CC / 256, 256, 0, stream>>>(x, w_jeff, w_cc, w_sf0, w_sf1, y7);

    // 2. z1 = y7 @ W1^T : (2048,512)x(2048,512)^T -> (2048,2048); 256 blocks
    gemm_nt<<<dim3(2048 / 128, 2048 / 128, 1), 256, 0, stream>>>(
        y7, W1, z1, M, 2048, 512, 512);

    // 3. IF + filter(sf2) in place on z1
    if_filter_kernel<<<NB * 2048 / 256, 256, 0, stream>>>(z1, 0, 1, w_sf2, 2048);

    // 4. z2 = z1 @ W2^T -> (2048,1024), split-K=2; 256 blocks
    gemm_nt<<<dim3(1024 / 128, 2048 / 128, ksplit2), 256, 0, stream>>>(
        z1, W2, z2p, M, 1024, 2048, 2048 / ksplit2);

    // 5. sum partials + IF + filter(sf3) -> z2p[0]
    if_filter_kernel<<<NB * 1024 / 256, 256, 0, stream>>>(
        z2p, (size_t)M * 1024, ksplit2, w_sf3, 1024);

    // 6. z3 = z2 @ W3^T -> (2048,512), split-K=4; 256 blocks (overlays z1)
    gemm_nt<<<dim3(512 / 128, 2048 / 128, 4), 256, 0, stream>>>(
        z2p, W3, z3p, M, 512, 1024, 1024 / 4);

    // 7. sum partials + IF (raw spikes) -> z3p[0]
    if_filter_kernel<<<NB * 512 / 256, 256, 0, stream>>>(
        z3p, (size_t)M * 512, 4, nullptr, 512);

    // 8. final dot + bias + cumsum
    final_kernel<<<NB, 64, 0, stream>>>(z3p, W_out, b_out, out);
}

// Round 5
// 358.570 us; speedup vs baseline: 1.2728x; 1.2728x over previous
//
#include <hip/hip_runtime.h>
#include <math.h>

#define T_STEPS 32
#define NB 64      // batch
#define CC 512     // channels
#define AA 32      // cc_acc size
#define MROWS (T_STEPS * NB)   // 2048 GEMM rows

typedef __attribute__((ext_vector_type(8))) short bf16x8;
typedef __attribute__((ext_vector_type(4))) float f32x4;

__device__ __forceinline__ float sig_decay(const float* wp) {
    // decay = 1 - sigmoid(w)
    return 1.0f - 1.0f / (1.0f + expf(-wp[0]));
}

__device__ __forceinline__ unsigned short f2bf_rne(float f) {
    unsigned int u = __float_as_uint(f);
    u += 0x7FFF + ((u >> 16) & 1);      // round-to-nearest-even
    return (unsigned short)(u >> 16);
}

// ---------------------------------------------------------------------------
// Split fp32 weights into 3 bf16 planes (hi, mid, lo).  w ~= h + m + l with
// residual ~2^-27|w|.  Binary spikes make each MFMA product exact, so the
// 3-plane MFMA GEMM reproduces fp32 accuracy.
// ---------------------------------------------------------------------------
__global__ __launch_bounds__(256) void split_w_kernel(
    const float* __restrict__ W, unsigned short* __restrict__ out, int n)
{
    int i = blockIdx.x * 256 + threadIdx.x;
    if (i >= n) return;
    float w = W[i];
    unsigned short h = f2bf_rne(w);
    float fh = __uint_as_float((unsigned int)h << 16);
    float r = w - fh;
    unsigned short m = f2bf_rne(r);
    float fm = __uint_as_float((unsigned int)m << 16);
    unsigned short l = f2bf_rne(r - fm);
    out[i] = h; out[n + i] = m; out[2 * n + i] = l;
}

// ---------------------------------------------------------------------------
// Front end: transpose + synapse(tau=2) + jeffress(2->32) + LIF(1.5) +
// synapse(sf0) + w_cc(32->1) + IF.  One thread per (n,c), loops t.
// spike_out != null: write raw IF spikes as bf16 (MFMA path; sf1 commutes
// past GEMM1).  Else legacy: apply sf1 filter, write fp32.
// ---------------------------------------------------------------------------
__global__ __launch_bounds__(256) void front_kernel(
    const float* __restrict__ x, const float* __restrict__ w_jeff,
    const float* __restrict__ w_cc, const float* __restrict__ w_sf0,
    const float* __restrict__ w_sf1,
    unsigned short* __restrict__ spike_out, float* __restrict__ filt_out)
{
    __shared__ float wj[2 * AA];
    __shared__ float wcc[AA];
    int tid = threadIdx.x;
    if (tid < 2 * AA) wj[tid] = w_jeff[tid];
    if (tid < AA) wcc[tid] = w_cc[tid];
    __syncthreads();

    int g = blockIdx.x * 256 + tid;     // n*CC + c
    int n = g >> 9;
    int c = g & (CC - 1);

    const float inv_lif = 1.0f / 1.5f;
    float d0 = sig_decay(w_sf0);
    float d1 = sig_decay(w_sf1);

    float s0 = 0.f, s1 = 0.f, v6 = 0.f, u1 = 0.f;
    float v[AA], u[AA];
#pragma unroll
    for (int a = 0; a < AA; a++) { v[a] = 0.f; u[a] = 0.f; }

    for (int t = 0; t < T_STEPS; t++) {
        const float* xp = x + (size_t)((t * NB + n) * 2) * CC + c;
        s0 = s0 * 0.5f + xp[0];
        s1 = s1 * 0.5f + xp[CC];
        float acc = 0.f;
#pragma unroll
        for (int a = 0; a < AA; a++) {
            float z  = wj[2 * a] * s0 + wj[2 * a + 1] * s1;
            float vv = v[a] + (z - v[a]) * inv_lif;
            bool  sp = vv >= 1.0f;
            v[a] = sp ? 0.0f : vv;
            float uu = u[a] * d0 + (sp ? 1.0f : 0.0f);
            u[a] = uu;
            acc += wcc[a] * uu;
        }
        v6 += acc;                                    // IFNode
        bool sp6 = v6 >= 1.0f;
        v6 = sp6 ? 0.0f : v6;
        size_t idx = (size_t)(t * NB + n) * CC + c;
        if (spike_out) {
            spike_out[idx] = sp6 ? (unsigned short)0x3F80 : (unsigned short)0;
        } else {
            u1 = u1 * d1 + (sp6 ? 1.0f : 0.0f);
            filt_out[idx] = u1;
        }
    }
}

// ---------------------------------------------------------------------------
// MFMA-path consumer: sum split-K parts of G = W·s, apply commuted input
// filter zf = zf*d + G[t], IF, emit spikes (bf16 for next GEMM or fp32).
// ---------------------------------------------------------------------------
__global__ __launch_bounds__(256) void if_spike_kernel(
    const float* __restrict__ G, size_t partStride, int nparts,
    const float* __restrict__ w_sf_in, int F,
    unsigned short* __restrict__ out_bf, float* __restrict__ out_f32)
{
    int tid = blockIdx.x * 256 + threadIdx.x;   // n*F + f
    const int NF = NB * F;
    float dz = sig_decay(w_sf_in);
    float zf = 0.f, v = 0.f;
    for (int t = 0; t < T_STEPS; t++) {
        size_t off = (size_t)t * NF + tid;
        float gsum = G[off];
        for (int p = 1; p < nparts; p++) gsum += G[p * partStride + off];
        zf = zf * dz + gsum;      // commuted synapse filter
        v += zf;                  // IF
        bool sp = v >= 1.0f;
        v = sp ? 0.0f : v;
        if (out_bf) out_bf[off] = sp ? (unsigned short)0x3F80 : (unsigned short)0;
        else        out_f32[off] = sp ? 1.0f : 0.0f;
    }
}

// ---------------------------------------------------------------------------
// Binary-A bf16 MFMA GEMM:  C(+split) = A(spikes, MxK bf16) @ B^T where B is
// 3 bf16 planes (N,K) summed into one fp32 accumulator (exact for binary A).
// 128x128 tile, BK=32, 256 threads = 4 waves; wave = 128m x 32n strip:
// acc[8][2] (64 VGPR), A-frags reused across 3 planes x 2 n-tiles.
// LDS rows padded to 20 dwords -> fragment reads conflict-clean.
// ---------------------------------------------------------------------------
__global__ __launch_bounds__(256) void bgemm(
    const unsigned short* __restrict__ A,   // M x K spikes (bf16)
    const unsigned short* __restrict__ B,   // 3 planes of N x K (bf16)
    float* __restrict__ C,                  // ksplit x M x N fp32
    int N, int K_total, int K_per)
{
    __shared__ __align__(16) unsigned int As[128 * 20];       // 10 KB
    __shared__ __align__(16) unsigned int Bs[3 * 128 * 20];   // 30 KB

    const int tid = threadIdx.x;
    const int w   = tid >> 6;         // wave 0..3
    const int L   = tid & 63;
    const int bm  = blockIdx.y * 128;
    const int bn  = blockIdx.x * 128;
    const int kbeg = blockIdx.z * K_per;

    f32x4 acc[8][2];
#pragma unroll
    for (int i = 0; i < 8; i++)
#pragma unroll
        for (int j = 0; j < 2; j++) acc[i][j] = (f32x4){0.f, 0.f, 0.f, 0.f};

    // staging: A 128x32bf16 = 512 chunks(16B), 2/thread; B 3x128x32 = 6/thread
    uint4 pa[2], pb[6];
    auto gload = [&](int k0) {
#pragma unroll
        for (int i = 0; i < 2; i++) {
            int idx = tid + i * 256;
            int r = idx >> 2, c = idx & 3;
            pa[i] = *(const uint4*)(A + (size_t)(bm + r) * K_total + k0 + c * 8);
        }
#pragma unroll
        for (int i = 0; i < 6; i++) {
            int idx = tid + i * 256;
            int p = idx >> 9, rem = idx & 511;
            int r = rem >> 2, c = rem & 3;
            pb[i] = *(const uint4*)(B + ((size_t)p * N + bn + r) * K_total + k0 + c * 8);
        }
    };
    auto lwrite = [&]() {
#pragma unroll
        for (int i = 0; i < 2; i++) {
            int idx = tid + i * 256;
            int r = idx >> 2, c = idx & 3;
            *(uint4*)&As[r * 20 + c * 4] = pa[i];
        }
#pragma unroll
        for (int i = 0; i < 6; i++) {
            int idx = tid + i * 256;
            int p = idx >> 9, rem = idx & 511;
            int r = rem >> 2, c = rem & 3;
            *(uint4*)&Bs[p * 2560 + r * 20 + c * 4] = pb[i];
        }
    };

    const int lrow = L & 15;
    const int lq   = L >> 4;

    gload(kbeg);
    const int nk = K_per / 32;
    for (int kt = 0; kt < nk; kt++) {
        lwrite();
        __syncthreads();
        if (kt + 1 < nk) gload(kbeg + (kt + 1) * 32);   // prefetch to regs

        bf16x8 a[8];
#pragma unroll
        for (int i = 0; i < 8; i++)
            a[i] = *(const bf16x8*)&As[(i * 16 + lrow) * 20 + lq * 4];
#pragma unroll
        for (int p = 0; p < 3; p++) {
#pragma unroll
            for (int j = 0; j < 2; j++) {
                bf16x8 b = *(const bf16x8*)
                    &Bs[p * 2560 + (w * 32 + j * 16 + lrow) * 20 + lq * 4];
#pragma unroll
                for (int i = 0; i < 8; i++)
                    acc[i][j] = __builtin_amdgcn_mfma_f32_16x16x32_bf16(
                        a[i], b, acc[i][j], 0, 0, 0);
            }
        }
        __syncthreads();
    }

    // C/D layout (m89-verified): col = lane&15, row = (lane>>4)*4 + reg
    float* Cp = C + (size_t)blockIdx.z * (size_t)MROWS * N;
#pragma unroll
    for (int i = 0; i < 8; i++) {
#pragma unroll
        for (int j = 0; j < 2; j++) {
            int col = bn + w * 32 + j * 16 + lrow;
            size_t base = (size_t)(bm + i * 16 + lq * 4) * N + col;
#pragma unroll
            for (int r = 0; r < 4; r++)
                Cp[base + (size_t)r * N] = acc[i][j][r];
        }
    }
}

// ---------------------------------------------------------------------------
// Legacy fp32 path (round-3, proven): used only if ws_size is too small.
// ---------------------------------------------------------------------------
__global__ __launch_bounds__(256) void if_filter_kernel(
    float* __restrict__ buf, size_t partStride, int nparts,
    const float* __restrict__ w_sf, int F)
{
    int tid = blockIdx.x * 256 + threadIdx.x;
    const int NF = NB * F;
    bool  filt = (w_sf != nullptr);
    float d = filt ? sig_decay(w_sf) : 0.0f;
    float v = 0.f, u = 0.f;
    for (int t = 0; t < T_STEPS; t++) {
        size_t off = (size_t)t * NF + tid;
        float zt = buf[off];
        for (int p = 1; p < nparts; p++) zt += buf[p * partStride + off];
        v += zt;
        bool sp = v >= 1.0f;
        v = sp ? 0.0f : v;
        float s = sp ? 1.0f : 0.0f;
        if (filt) { u = u * d + s; buf[off] = u; }
        else      { buf[off] = s; }
    }
}

__global__ __launch_bounds__(256) void gemm_nt(
    const float* __restrict__ A, const float* __restrict__ B,
    float* __restrict__ C, int M, int N, int K_total, int K_per)
{
    constexpr int BM = 64, BN = 64, BK = 32;
    __shared__ float As[BK][BM + 4];
    __shared__ float Bs[BK][BN + 4];
    const int tid = threadIdx.x;
    const int tx  = tid & 15;
    const int ty  = tid >> 4;
    const int bm  = blockIdx.y * BM;
    const int bn  = blockIdx.x * BN;
    const int kbeg = blockIdx.z * K_per;
    float acc[4][4];
#pragma unroll
    for (int i = 0; i < 4; i++)
#pragma unroll
        for (int j = 0; j < 4; j++) acc[i][j] = 0.f;
    const int lrow = tid >> 3;
    const int lkq  = tid & 7;
    for (int kt = 0; kt < K_per; kt += BK) {
        int k0 = kbeg + kt;
        __syncthreads();
#pragma unroll
        for (int i = 0; i < 2; i++) {
            int row = lrow + i * 32;
            float4 av = *(const float4*)(A + (size_t)(bm + row) * K_total + k0 + lkq * 4);
            As[lkq * 4 + 0][row] = av.x;
            As[lkq * 4 + 1][row] = av.y;
            As[lkq * 4 + 2][row] = av.z;
            As[lkq * 4 + 3][row] = av.w;
            float4 bv = *(const float4*)(B + (size_t)(bn + row) * K_total + k0 + lkq * 4);
            Bs[lkq * 4 + 0][row] = bv.x;
            Bs[lkq * 4 + 1][row] = bv.y;
            Bs[lkq * 4 + 2][row] = bv.z;
            Bs[lkq * 4 + 3][row] = bv.w;
        }
        __syncthreads();
#pragma unroll
        for (int kk = 0; kk < BK; kk++) {
            float4 a0 = *(const float4*)&As[kk][ty * 4];
            float4 b0 = *(const float4*)&Bs[kk][tx * 4];
            float ar[4] = {a0.x, a0.y, a0.z, a0.w};
            float br[4] = {b0.x, b0.y, b0.z, b0.w};
#pragma unroll
            for (int i = 0; i < 4; i++)
#pragma unroll
                for (int j = 0; j < 4; j++) acc[i][j] += ar[i] * br[j];
        }
    }
    float* Cp = C + (size_t)blockIdx.z * (size_t)M * N;
#pragma unroll
    for (int i = 0; i < 4; i++) {
        float4 o;
        o.x = acc[i][0]; o.y = acc[i][1]; o.z = acc[i][2]; o.w = acc[i][3];
        *(float4*)(Cp + (size_t)(bm + ty * 4 + i) * N + bn + tx * 4) = o;
    }
}

// ---------------------------------------------------------------------------
// Final: out[t,n] = cumsum_t( dot(s3[t,n,:512], W_out) + b ).  One wave per n.
// ---------------------------------------------------------------------------
__global__ __launch_bounds__(64) void final_kernel(
    const float* __restrict__ y15, const float* __restrict__ W_out,
    const float* __restrict__ b_out, float* __restrict__ out)
{
    int n = blockIdx.x;
    int lane = threadIdx.x;
    float w[8];
#pragma unroll
    for (int j = 0; j < 8; j++) w[j] = W_out[lane + j * 64];
    float b = b_out[0];
    float cum = 0.f;
    for (int t = 0; t < T_STEPS; t++) {
        const float* yp = y15 + (size_t)(t * NB + n) * 512;
        float p = 0.f;
#pragma unroll
        for (int j = 0; j < 8; j++) p += yp[lane + j * 64] * w[j];
#pragma unroll
        for (int off = 32; off > 0; off >>= 1) p += __shfl_down(p, off);
        if (lane == 0) {
            cum += p + b;
            out[t * NB + n] = cum;
        }
    }
}

extern "C" void kernel_launch(void* const* d_in, const int* in_sizes, int n_in,
                              void* d_out, int out_size, void* d_ws, size_t ws_size,
                              hipStream_t stream) {
    (void)in_sizes; (void)n_in; (void)out_size;
    const float* x      = (const float*)d_in[0];
    const float* w_jeff = (const float*)d_in[1];
    const float* w_cc   = (const float*)d_in[2];
    const float* w_sf0  = (const float*)d_in[3];
    const float* W1     = (const float*)d_in[4];
    const float* w_sf1  = (const float*)d_in[5];
    const float* W2     = (const float*)d_in[6];
    const float* w_sf2  = (const float*)d_in[7];
    const float* W3     = (const float*)d_in[8];
    const float* w_sf3  = (const float*)d_in[9];
    const float* W_out  = (const float*)d_in[10];
    const float* b_out  = (const float*)d_in[11];
    float* out = (float*)d_out;
    const int M = MROWS;   // 2048

    // -------- MFMA path workspace (bytes): ~74.5 MB --------
    const size_t nW1 = (size_t)2048 * 512, nW2 = (size_t)1024 * 2048, nW3 = (size_t)512 * 1024;
    size_t need =
        (3 * nW1 + 3 * nW2 + 3 * nW3) * 2     // weight split planes
        + (size_t)M * 512 * 2                 // s6
        + (size_t)M * 2048 * 4                // G1 (reused as G3: 4 x M x 512)
        + (size_t)M * 2048 * 2                // s8
        + 2 * (size_t)M * 1024 * 4            // G2 (splitK=2)
        + (size_t)M * 1024 * 2                // s10
        + (size_t)M * 512 * 4;                // s12

    if (ws_size >= need) {
        // ---------------- MFMA (binary spikes x bf16-split-3) ----------------
        unsigned short* Ws1 = (unsigned short*)d_ws;
        unsigned short* Ws2 = Ws1 + 3 * nW1;
        unsigned short* Ws3 = Ws2 + 3 * nW2;
        unsigned short* s6  = Ws3 + 3 * nW3;
        float* G1  = (float*)(s6 + (size_t)M * 512);
        float* G2  = G1 + (size_t)M * 2048;
        unsigned short* s8  = (unsigned short*)(G2 + 2 * (size_t)M * 1024);
        unsigned short* s10 = s8 + (size_t)M * 2048;
        float* s12 = (float*)(s10 + (size_t)M * 1024);
        float* G3  = G1;   // overlay: G1 dead once s8 exists; same 16 MB

        split_w_kernel<<<(int)((3 * 0 + nW1 + 255) / 256), 256, 0, stream>>>(W1, Ws1, (int)nW1);
        split_w_kernel<<<(int)((nW2 + 255) / 256), 256, 0, stream>>>(W2, Ws2, (int)nW2);
        split_w_kernel<<<(int)((nW3 + 255) / 256), 256, 0, stream>>>(W3, Ws3, (int)nW3);

        front_kernel<<<NB * CC / 256, 256, 0, stream>>>(
            x, w_jeff, w_cc, w_sf0, w_sf1, s6, nullptr);

        // GEMM1: G1 = s6 @ W1^T  (K=512), 16x16x1 = 256 blocks
        bgemm<<<dim3(2048 / 128, M / 128, 1), 256, 0, stream>>>(s6, Ws1, G1, 2048, 512, 512);
        if_spike_kernel<<<NB * 2048 / 256, 256, 0, stream>>>(
            G1, 0, 1, w_sf1, 2048, s8, nullptr);

        // GEMM2: G2 = s8 @ W2^T  (K=2048, splitK=2), 8x16x2 = 256 blocks
        bgemm<<<dim3(1024 / 128, M / 128, 2), 256, 0, stream>>>(s8, Ws2, G2, 1024, 2048, 1024);
        if_spike_kernel<<<NB * 1024 / 256, 256, 0, stream>>>(
            G2, (size_t)M * 1024, 2, w_sf2, 1024, s10, nullptr);

        // GEMM3: G3 = s10 @ W3^T (K=1024, splitK=4), 4x16x4 = 256 blocks
        bgemm<<<dim3(512 / 128, M / 128, 4), 256, 0, stream>>>(s10, Ws3, G3, 512, 1024, 256);
        if_spike_kernel<<<NB * 512 / 256, 256, 0, stream>>>(
            G3, (size_t)M * 512, 4, w_sf3, 512, nullptr, s12);

        final_kernel<<<NB, 64, 0, stream>>>(s12, W_out, b_out, out);
    } else {
        // ---------------- legacy fp32 path (round-3) ----------------
        float* y7  = (float*)d_ws;
        float* z1  = y7 + (size_t)M * 512;
        float* z2p = z1 + (size_t)M * 2048;
        float* z3p = z1;
        size_t need2 = ((size_t)M * 512 + (size_t)M * 2048 + 2 * (size_t)M * 1024) * 4;
        const int ksplit2 = (ws_size >= need2) ? 2 : 1;

        front_kernel<<<NB * CC / 256, 256, 0, stream>>>(
            x, w_jeff, w_cc, w_sf0, w_sf1, nullptr, y7);
        gemm_nt<<<dim3(2048 / 64, 2048 / 64, 1), 256, 0, stream>>>(
            y7, W1, z1, M, 2048, 512, 512);
        if_filter_kernel<<<NB * 2048 / 256, 256, 0, stream>>>(z1, 0, 1, w_sf2, 2048);
        gemm_nt<<<dim3(1024 / 64, 2048 / 64, ksplit2), 256, 0, stream>>>(
            z1, W2, z2p, M, 1024, 2048, 2048 / ksplit2);
        if_filter_kernel<<<NB * 1024 / 256, 256, 0, stream>>>(
            z2p, (size_t)M * 1024, ksplit2, w_sf3, 1024);
        gemm_nt<<<dim3(512 / 64, 2048 / 64, 4), 256, 0, stream>>>(
            z2p, W3, z3p, M, 512, 1024, 1024 / 4);
        if_filter_kernel<<<NB * 512 / 256, 256, 0, stream>>>(
            z3p, (size_t)M * 512, 4, nullptr, 512);
        final_kernel<<<NB, 64, 0, stream>>>(z3p, W_out, b_out, out);
    }
}